// Round 1
// baseline (143.601 us; speedup 1.0000x reference)
//
#include <hip/hip_runtime.h>
#include <stdint.h>

// Problem constants
#define M_ROWS 16000      // B*T = 8*2000
#define M_PAD  16384
#define D_IN   320
#define E_DIM  16
#define K_CB   8192
#define KCHUNK 256                    // codewords per block
#define NKCHUNK (K_CB / KCHUNK)       // 32 k-chunks
#define RPB    1024                   // rows per score block
#define RPT    4                      // rows per thread

// ---------------- Projection: X[row][e] = sum_d hs[row][d] * P[d][e] ----------------
// grid 250 x 256 threads; thread -> (row = bid*64 + t/4, e-quad = t&3)
__global__ __launch_bounds__(256) void proj_kernel(const float* __restrict__ hs,
                                                   const float* __restrict__ P,
                                                   float* __restrict__ X) {
    int t   = threadIdx.x;
    int row = blockIdx.x * 64 + (t >> 2);
    int eq  = t & 3;
    if (row >= M_ROWS) return;
    const float* hrow = hs + (size_t)row * D_IN;
    float ax = 0.f, ay = 0.f, az = 0.f, aw = 0.f;
    #pragma unroll 4
    for (int d = 0; d < D_IN; d += 4) {
        float4 h4 = *reinterpret_cast<const float4*>(hrow + d);
        float4 p0 = *reinterpret_cast<const float4*>(P + (size_t)(d + 0) * E_DIM + eq * 4);
        float4 p1 = *reinterpret_cast<const float4*>(P + (size_t)(d + 1) * E_DIM + eq * 4);
        float4 p2 = *reinterpret_cast<const float4*>(P + (size_t)(d + 2) * E_DIM + eq * 4);
        float4 p3 = *reinterpret_cast<const float4*>(P + (size_t)(d + 3) * E_DIM + eq * 4);
        ax += h4.x * p0.x + h4.y * p1.x + h4.z * p2.x + h4.w * p3.x;
        ay += h4.x * p0.y + h4.y * p1.y + h4.z * p2.y + h4.w * p3.y;
        az += h4.x * p0.z + h4.y * p1.z + h4.z * p2.z + h4.w * p3.z;
        aw += h4.x * p0.w + h4.y * p1.w + h4.z * p2.w + h4.w * p3.w;
    }
    float4 acc = make_float4(ax, ay, az, aw);
    *reinterpret_cast<float4*>(X + (size_t)row * E_DIM + eq * 4) = acc;
}

// ---------------- keys init ----------------
__global__ __launch_bounds__(256) void init_keys(unsigned long long* __restrict__ keys) {
    int i = blockIdx.x * 256 + threadIdx.x;
    if (i < M_PAD) keys[i] = 0ull;
}

// ---------------- Fused score + argmax ----------------
// grid (16 row-blocks, 32 k-chunks) x 256 threads; thread owns 4 rows (stride 256).
// Running best per row over this chunk; combine across chunks via u64 atomicMax on
// key = (monotonic(float) << 32) | ~idx  -> max picks larger score, then LOWER index
// on exact float ties (matches numpy first-argmax semantics).
__global__ __launch_bounds__(256) void score_kernel(const float* __restrict__ X,
                                                    const float* __restrict__ CB,
                                                    unsigned long long* __restrict__ keys) {
    __shared__ float4 cbl[KCHUNK * 4];   // 256 codewords x 16 floats = 16 KB
    int t  = threadIdx.x;
    int rb = blockIdx.x;     // 0..15
    int kc = blockIdx.y;     // 0..31

    // Stage this k-chunk of CB into LDS (coalesced float4 loads).
    const float4* cbg = reinterpret_cast<const float4*>(CB + (size_t)kc * KCHUNK * E_DIM);
    #pragma unroll
    for (int i = 0; i < 4; ++i) cbl[t + 256 * i] = cbg[t + 256 * i];

    // Load this thread's 4 projected rows into registers.
    float4 x[RPT][4];
    int row0 = rb * RPB + t;
    #pragma unroll
    for (int j = 0; j < RPT; ++j) {
        const float4* xr = reinterpret_cast<const float4*>(X + (size_t)(row0 + 256 * j) * E_DIM);
        x[j][0] = xr[0]; x[j][1] = xr[1]; x[j][2] = xr[2]; x[j][3] = xr[3];
    }
    float best[RPT];
    int   bidx[RPT];
    #pragma unroll
    for (int j = 0; j < RPT; ++j) { best[j] = -3.0e38f; bidx[j] = 0; }

    __syncthreads();

    int kbase = kc * KCHUNK;
    #pragma unroll 2
    for (int kk = 0; kk < KCHUNK; ++kk) {
        float4 c0 = cbl[kk * 4 + 0];
        float4 c1 = cbl[kk * 4 + 1];
        float4 c2 = cbl[kk * 4 + 2];
        float4 c3 = cbl[kk * 4 + 3];
        #pragma unroll
        for (int j = 0; j < RPT; ++j) {
            float t0 = x[j][0].x * c0.x + x[j][0].y * c0.y + x[j][0].z * c0.z + x[j][0].w * c0.w;
            float t1 = x[j][1].x * c1.x + x[j][1].y * c1.y + x[j][1].z * c1.z + x[j][1].w * c1.w;
            float t2 = x[j][2].x * c2.x + x[j][2].y * c2.y + x[j][2].z * c2.z + x[j][2].w * c2.w;
            float t3 = x[j][3].x * c3.x + x[j][3].y * c3.y + x[j][3].z * c3.z + x[j][3].w * c3.w;
            float s  = (t0 + t1) + (t2 + t3);
            if (s > best[j]) { best[j] = s; bidx[j] = kbase + kk; }
        }
    }

    #pragma unroll
    for (int j = 0; j < RPT; ++j) {
        int row = row0 + 256 * j;
        if (row < M_ROWS) {
            unsigned u    = __float_as_uint(best[j]);
            unsigned mono = (u & 0x80000000u) ? ~u : (u | 0x80000000u);
            unsigned long long key =
                ((unsigned long long)mono << 32) | (unsigned)(~(unsigned)bidx[j]);
            atomicMax(keys + row, key);
        }
    }
}

// ---------------- Decode keys -> int32 indices ----------------
__global__ __launch_bounds__(256) void decode_kernel(const unsigned long long* __restrict__ keys,
                                                     int* __restrict__ out) {
    int i = blockIdx.x * 256 + threadIdx.x;
    if (i < M_ROWS) out[i] = (int)(~(unsigned)(keys[i] & 0xFFFFFFFFull));
}

extern "C" void kernel_launch(void* const* d_in, const int* in_sizes, int n_in,
                              void* d_out, int out_size, void* d_ws, size_t ws_size,
                              hipStream_t stream) {
    const float* hs = (const float*)d_in[0];   // [8,2000,320]
    const float* P  = (const float*)d_in[1];   // [1,320,16]
    const float* CB = (const float*)d_in[2];   // [1,8192,16]
    int* out = (int*)d_out;                    // [8,1,2000] int32

    float* X = (float*)d_ws;                                        // M_PAD x 16 floats = 1 MB
    unsigned long long* keys =
        (unsigned long long*)((char*)d_ws + (size_t)M_PAD * E_DIM * sizeof(float));

    proj_kernel<<<dim3(250), dim3(256), 0, stream>>>(hs, P, X);
    init_keys<<<dim3(M_PAD / 256), dim3(256), 0, stream>>>(keys);
    score_kernel<<<dim3(16, NKCHUNK), dim3(256), 0, stream>>>(X, CB, keys);
    decode_kernel<<<dim3((M_ROWS + 255) / 256), dim3(256), 0, stream>>>(keys, out);
}

// Round 2
// 69.967 us; speedup vs baseline: 2.0524x; 2.0524x over previous
//
#include <hip/hip_runtime.h>
#include <stdint.h>

// Problem constants
#define M_ROWS   16000        // B*T
#define N_RT     1000         // real 16-row tiles (16000/16 exactly)
#define N_RT_PAD 1008         // padded to 63 row-blocks of 16 tiles
#define D_IN     320
#define E_DIM    16
#define K_CB     8192
#define NKT      512          // 8192/16 k-tiles
#define NCHUNK   32           // k-chunks (16 k-tiles each)
#define KT_PER_CHUNK 16

typedef __attribute__((ext_vector_type(8))) short bf16x8;
typedef __attribute__((ext_vector_type(4))) float f32x4;

// Workspace layout (bytes)
#define XA_OFF   0u                       // [1008 tiles][64 lanes][8 bf16]  (h|m)
#define XB_OFF   1032192u                 // same shape                       (l|h)
#define CBA_OFF  2064384u                 // [512 ktiles][64 lanes][8 bf16]  (h'|m')
#define CBC_OFF  2588672u                 // same                             (h'|l')
#define KEYS_OFF 3112960u                 // [16128] u64

__device__ __forceinline__ unsigned short f2bf(float x) {
    union { float f; unsigned u; } v; v.f = x;
    unsigned r = v.u + 0x7FFFu + ((v.u >> 16) & 1u);   // round-to-nearest-even
    return (unsigned short)(r >> 16);
}
__device__ __forceinline__ float bf2f(unsigned short b) {
    union { unsigned u; float f; } v; v.u = ((unsigned)b) << 16; return v.f;
}

// ---------- Projection + exact 3-way bf16 split + A-fragment packing ----------
// thread -> (row = bid*64 + t/4, eq = t&3 owning e = 4*eq..4*eq+3)
// A-frag layout (16x16x32): lane l holds A[l&15][k=(l>>4)*8+j], j=0..7.
__global__ __launch_bounds__(256) void proj_pack(const float* __restrict__ hs,
                                                 const float* __restrict__ P,
                                                 unsigned short* __restrict__ Xa,
                                                 unsigned short* __restrict__ Xb) {
    int t   = threadIdx.x;
    int row = blockIdx.x * 64 + (t >> 2);
    int eq  = t & 3;
    if (row >= M_ROWS) return;
    const float* hrow = hs + (size_t)row * D_IN;
    float ax = 0.f, ay = 0.f, az = 0.f, aw = 0.f;
    #pragma unroll 4
    for (int d = 0; d < D_IN; d += 4) {
        float4 h4 = *reinterpret_cast<const float4*>(hrow + d);
        float4 p0 = *reinterpret_cast<const float4*>(P + (size_t)(d + 0) * E_DIM + eq * 4);
        float4 p1 = *reinterpret_cast<const float4*>(P + (size_t)(d + 1) * E_DIM + eq * 4);
        float4 p2 = *reinterpret_cast<const float4*>(P + (size_t)(d + 2) * E_DIM + eq * 4);
        float4 p3 = *reinterpret_cast<const float4*>(P + (size_t)(d + 3) * E_DIM + eq * 4);
        ax += h4.x * p0.x + h4.y * p1.x + h4.z * p2.x + h4.w * p3.x;
        ay += h4.x * p0.y + h4.y * p1.y + h4.z * p2.y + h4.w * p3.y;
        az += h4.x * p0.z + h4.y * p1.z + h4.z * p2.z + h4.w * p3.z;
        aw += h4.x * p0.w + h4.y * p1.w + h4.z * p2.w + h4.w * p3.w;
    }
    float v[4] = {ax, ay, az, aw};
    ushort4 h, m, l;
    unsigned short* hp = (unsigned short*)&h;
    unsigned short* mp = (unsigned short*)&m;
    unsigned short* lp = (unsigned short*)&l;
    #pragma unroll
    for (int i = 0; i < 4; ++i) {
        unsigned short hb = f2bf(v[i]);      float r1 = v[i] - bf2f(hb);
        unsigned short mb = f2bf(r1);        float r2 = r1 - bf2f(mb);
        unsigned short lb = f2bf(r2);        // exact: v = h + m + l
        hp[i] = hb; mp[i] = mb; lp[i] = lb;
    }
    int rt = row >> 4, rl = row & 15;
    int g  = eq >> 1;            // k-group of e0=4*eq (0..1)
    int j0 = (eq & 1) * 4;
    size_t base = (size_t)rt * 512;          // ushorts per tile = 64*8
    // Xa = [h | m]: h at k=e (group g), m at k=e+16 (group 2+g)
    *reinterpret_cast<ushort4*>(Xa + base + ((g    ) * 16 + rl) * 8 + j0) = h;
    *reinterpret_cast<ushort4*>(Xa + base + ((2 + g) * 16 + rl) * 8 + j0) = m;
    // Xb = [l | h]
    *reinterpret_cast<ushort4*>(Xb + base + ((g    ) * 16 + rl) * 8 + j0) = l;
    *reinterpret_cast<ushort4*>(Xb + base + ((2 + g) * 16 + rl) * 8 + j0) = h;
}

// ---------- Codebook split + B-fragment packing ----------
// B-frag layout (16x16x32): lane l holds B[k=(l>>4)*8+j][l&15].
__global__ __launch_bounds__(256) void cb_pack(const float* __restrict__ CB,
                                               unsigned short* __restrict__ CBa,
                                               unsigned short* __restrict__ CBc) {
    int t  = threadIdx.x;
    int c  = blockIdx.x * 64 + (t >> 2);     // codeword
    int eq = t & 3;
    float4 v4 = *reinterpret_cast<const float4*>(CB + (size_t)c * E_DIM + eq * 4);
    float v[4] = {v4.x, v4.y, v4.z, v4.w};
    ushort4 h, m, l;
    unsigned short* hp = (unsigned short*)&h;
    unsigned short* mp = (unsigned short*)&m;
    unsigned short* lp = (unsigned short*)&l;
    #pragma unroll
    for (int i = 0; i < 4; ++i) {
        unsigned short hb = f2bf(v[i]);      float r1 = v[i] - bf2f(hb);
        unsigned short mb = f2bf(r1);        float r2 = r1 - bf2f(mb);
        unsigned short lb = f2bf(r2);
        hp[i] = hb; mp[i] = mb; lp[i] = lb;
    }
    int kt = c >> 4, cl = c & 15;
    int g  = eq >> 1;
    int j0 = (eq & 1) * 4;
    size_t base = (size_t)kt * 512;
    // CBa = [h' | m']
    *reinterpret_cast<ushort4*>(CBa + base + ((g    ) * 16 + cl) * 8 + j0) = h;
    *reinterpret_cast<ushort4*>(CBa + base + ((2 + g) * 16 + cl) * 8 + j0) = m;
    // CBc = [h' | l']
    *reinterpret_cast<ushort4*>(CBc + base + ((g    ) * 16 + cl) * 8 + j0) = h;
    *reinterpret_cast<ushort4*>(CBc + base + ((2 + g) * 16 + cl) * 8 + j0) = l;
}

__global__ __launch_bounds__(256) void init_keys(unsigned long long* __restrict__ keys) {
    int i = blockIdx.x * 256 + threadIdx.x;
    if (i < 16 * N_RT_PAD) keys[i] = 0ull;
}

// ---------- MFMA score + fused argmax ----------
// grid (63 row-blocks, 32 k-chunks) x 256 threads (4 waves).
// Wave owns 4 row-tiles (64 rows); per k-tile: 3 chained MFMAs give full
// fp32-precision scores; per-lane stripe argmax; shfl_xor reduce; u64 atomicMax.
__global__ __launch_bounds__(256) void score_kernel(const unsigned short* __restrict__ Xa,
                                                    const unsigned short* __restrict__ Xb,
                                                    const unsigned short* __restrict__ CBa,
                                                    const unsigned short* __restrict__ CBc,
                                                    unsigned long long* __restrict__ keys) {
    int t    = threadIdx.x;
    int lane = t & 63;
    int w    = t >> 6;
    int rb   = blockIdx.x;    // 0..62
    int kc   = blockIdx.y;    // 0..31
    int rt0  = rb * 16 + w * 4;

    bf16x8 a_hm[4], a_lh[4];
    #pragma unroll
    for (int r = 0; r < 4; ++r) {
        a_hm[r] = *reinterpret_cast<const bf16x8*>(Xa + ((size_t)(rt0 + r) * 64 + lane) * 8);
        a_lh[r] = *reinterpret_cast<const bf16x8*>(Xb + ((size_t)(rt0 + r) * 64 + lane) * 8);
    }
    float best[4][4];
    int   bidx[4][4];
    #pragma unroll
    for (int r = 0; r < 4; ++r)
        #pragma unroll
        for (int i = 0; i < 4; ++i) { best[r][i] = -3.0e38f; bidx[r][i] = 0; }

    const unsigned short* pa = CBa + (size_t)kc * KT_PER_CHUNK * 512;
    const unsigned short* pc = CBc + (size_t)kc * KT_PER_CHUNK * 512;
    int lsw = lane ^ 32;      // swapped-half lane for the [m'|h'] operand

    #pragma unroll 2
    for (int kt = 0; kt < KT_PER_CHUNK; ++kt) {
        bf16x8 b1 = *reinterpret_cast<const bf16x8*>(pa + (kt * 64 + lane) * 8);
        bf16x8 b2 = *reinterpret_cast<const bf16x8*>(pa + (kt * 64 + lsw ) * 8);
        bf16x8 b3 = *reinterpret_cast<const bf16x8*>(pc + (kt * 64 + lane) * 8);
        #pragma unroll
        for (int r = 0; r < 4; ++r) {
            f32x4 acc = {0.f, 0.f, 0.f, 0.f};
            acc = __builtin_amdgcn_mfma_f32_16x16x32_bf16(a_hm[r], b1, acc, 0, 0, 0); // hh+mm
            acc = __builtin_amdgcn_mfma_f32_16x16x32_bf16(a_hm[r], b2, acc, 0, 0, 0); // hm+mh
            acc = __builtin_amdgcn_mfma_f32_16x16x32_bf16(a_lh[r], b3, acc, 0, 0, 0); // lh+hl
            #pragma unroll
            for (int i = 0; i < 4; ++i) {
                bool gt = acc[i] > best[r][i];
                best[r][i] = gt ? acc[i] : best[r][i];
                bidx[r][i] = gt ? kt     : bidx[r][i];
            }
        }
    }

    // cross-lane argmax reduce over the 16 columns of each row, then atomic combine
    int colc = lane & 15;
    #pragma unroll
    for (int r = 0; r < 4; ++r) {
        #pragma unroll
        for (int i = 0; i < 4; ++i) {
            float s  = best[r][i];
            int   kg = kc * 256 + bidx[r][i] * 16 + colc;   // global codeword idx
            #pragma unroll
            for (int off = 1; off <= 8; off <<= 1) {
                float os  = __shfl_xor(s, off, 64);
                int   okg = __shfl_xor(kg, off, 64);
                bool take = (os > s) || (os == s && okg < kg);
                s  = take ? os  : s;
                kg = take ? okg : kg;
            }
            if (colc == 0) {
                int row = (rt0 + r) * 16 + (lane >> 4) * 4 + i;  // C: row=(l>>4)*4+reg
                unsigned u    = __float_as_uint(s);
                unsigned mono = (u & 0x80000000u) ? ~u : (u | 0x80000000u);
                unsigned long long key =
                    ((unsigned long long)mono << 32) | (unsigned)(~(unsigned)kg);
                atomicMax(keys + row, key);
            }
        }
    }
}

__global__ __launch_bounds__(256) void decode_kernel(const unsigned long long* __restrict__ keys,
                                                     int* __restrict__ out) {
    int i = blockIdx.x * 256 + threadIdx.x;
    if (i < M_ROWS) out[i] = (int)(~(unsigned)(keys[i] & 0xFFFFFFFFull));
}

extern "C" void kernel_launch(void* const* d_in, const int* in_sizes, int n_in,
                              void* d_out, int out_size, void* d_ws, size_t ws_size,
                              hipStream_t stream) {
    const float* hs = (const float*)d_in[0];   // [8,2000,320]
    const float* P  = (const float*)d_in[1];   // [1,320,16]
    const float* CB = (const float*)d_in[2];   // [1,8192,16]
    int* out = (int*)d_out;                    // [8,1,2000] int32

    char* ws = (char*)d_ws;
    unsigned short* Xa  = (unsigned short*)(ws + XA_OFF);
    unsigned short* Xb  = (unsigned short*)(ws + XB_OFF);
    unsigned short* CBa = (unsigned short*)(ws + CBA_OFF);
    unsigned short* CBc = (unsigned short*)(ws + CBC_OFF);
    unsigned long long* keys = (unsigned long long*)(ws + KEYS_OFF);

    proj_pack<<<dim3(250), dim3(256), 0, stream>>>(hs, P, Xa, Xb);
    cb_pack<<<dim3(K_CB / 64), dim3(256), 0, stream>>>(CB, CBa, CBc);
    init_keys<<<dim3((16 * N_RT_PAD) / 256), dim3(256), 0, stream>>>(keys);
    score_kernel<<<dim3(63, NCHUNK), dim3(256), 0, stream>>>(Xa, Xb, CBa, CBc, keys);
    decode_kernel<<<dim3(63), dim3(256), 0, stream>>>(keys, out);
}